// Round 4
// baseline (2401.985 us; speedup 1.0000x reference)
//
#include <hip/hip_runtime.h>

#define B_ 8
#define T_ 14
#define HH 64
#define WW 64
#define CC 64
#define IMG (HH*WW*CC)  // 262144 elems per (b,t) image
#define NBLK (B_ * HH)  // 512 persistent blocks

typedef __attribute__((ext_vector_type(8))) short short8;
typedef __attribute__((ext_vector_type(4))) float floatx4;

// ws layout (bytes):
//   [0, 589824)        Wt: bf16 weights in MFMA B-fragment-major order
//   [1 MB, 5 MB)       h ping bf16 [8][64][64][64]  (linear)
//   [5 MB, 9 MB)       h pong bf16                   (linear)
//   [9 MB, +64)        grid-barrier state {cnt, gen}
// (c state lives in registers of the persistent kernel)
#define WT_OFF   0
#define H0_OFF   (1u << 20)
#define H1_OFF   (H0_OFF + 4u * 1024 * 1024)
#define BAR_OFF  (H1_OFF + 4u * 1024 * 1024)

__device__ __forceinline__ unsigned short bf16_of(float f) {
    unsigned int x = __float_as_uint(f);
    unsigned int r = (x + 0x7FFFu + ((x >> 16) & 1u)) >> 16;  // RTNE
    return (unsigned short)r;
}
__device__ __forceinline__ unsigned int pack2(float a, float b) {
    return (unsigned int)bf16_of(a) | ((unsigned int)bf16_of(b) << 16);
}
__device__ __forceinline__ float hsig(float z) {
    return fminf(fmaxf(fmaf(z, 0.2f, 0.5f), 0.0f), 1.0f);
}
__device__ __forceinline__ float tanh_fast(float v) {
    float e = __expf(2.0f * v);
    return 1.0f - 2.0f / (e + 1.0f);
}

// Software grid barrier (plain launch; no cooperative API, graph-capture safe).
// Requires all NBLK blocks co-resident: __launch_bounds__(256,2) + 66.5KB LDS
// -> exactly 2 blocks/CU x 256 CU = 512 = grid. Spin is bounded so a
// residency surprise terminates (wrong answer) instead of hanging the bench.
__device__ __forceinline__ void grid_barrier(unsigned* cnt, unsigned* gen) {
    __syncthreads();
    if (threadIdx.x == 0) {
        __threadfence();   // device-scope release of this block's h-row stores
        unsigned g = __hip_atomic_load(gen, __ATOMIC_ACQUIRE, __HIP_MEMORY_SCOPE_AGENT);
        unsigned v = __hip_atomic_fetch_add(cnt, 1u, __ATOMIC_ACQ_REL, __HIP_MEMORY_SCOPE_AGENT);
        if (v == (unsigned)NBLK - 1u) {
            __hip_atomic_store(cnt, 0u, __ATOMIC_RELAXED, __HIP_MEMORY_SCOPE_AGENT);
            __hip_atomic_store(gen, g + 1u, __ATOMIC_RELEASE, __HIP_MEMORY_SCOPE_AGENT);
        } else {
            for (unsigned spin = 0; spin < 5000000u; ++spin) {
                if (__hip_atomic_load(gen, __ATOMIC_ACQUIRE,
                                      __HIP_MEMORY_SCOPE_AGENT) != g) break;
            }
        }
    }
    __syncthreads();
}

// Repack Wx,Wh [3,3,64,256] fp32 -> bf16 B-fragment-major:
// chunk fc = ((src*9+tap)*2+g)*16 + ntile ; element [lane][j] (j=0..7 contiguous)
// value = W[tap*64 + (g*32 + (lane>>4)*8 + j)]*256 + ntile*16 + (lane&15)
__global__ void repack_weights(const float* __restrict__ Wx,
                               const float* __restrict__ Wh,
                               unsigned short* __restrict__ Wt,
                               unsigned* __restrict__ bar) {
    if (blockIdx.x == 0 && threadIdx.x == 0) { bar[0] = 0u; bar[1] = 0u; }
    int u = blockIdx.x * 256 + threadIdx.x;    // 36864 threads
    int l  = u & 63;
    int nt = (u >> 6) & 15;
    int g  = (u >> 10) & 1;
    int st = u >> 11;                          // src*9 + tap, 0..17
    const float* W = (st < 9) ? Wx : Wh;
    int tap = (st < 9) ? st : st - 9;
    int n  = nt * 16 + (l & 15);
    int c0 = g * 32 + (l >> 4) * 8;
    unsigned short tmp[8];
    #pragma unroll
    for (int j = 0; j < 8; ++j) {
        tmp[j] = bf16_of(W[(tap * 64 + c0 + j) * 256 + n]);
    }
    *(uint4*)(Wt + (size_t)u * 8) = *(const uint4*)tmp;
}

// LDS A-tile: bf16 [src 2][ky 3][col 66][ch 64]; col 0 and 65 are zero halo.
// XOR-swizzled: logical (col, c) lives at element (col, c ^ ((col&7)<<3)).
// Both staging writes and K-loop reads apply the same XOR (both-sides rule).
#define AT(s, r, col, c) ((((s) * 3 + (r)) * 66 + (col)) * 64 + (c))

// Persistent ConvLSTM: one block owns image row (b,y) for ALL timesteps.
// Per step: implicit GEMM M=64 px, N=256 gate-ch, K=18 taps x 64.
// c state lives in registers (16 fp32/thread). h exchanged via global +
// software grid barrier (device-scope fences cover cross-XCD visibility).
__global__ __launch_bounds__(256, 2) void lstm_persistent(
    const float* __restrict__ x,              // [8,14,64,64,64] fp32
    const unsigned short* __restrict__ Wt,    // repacked bf16 weights
    const float* __restrict__ bias,           // [256] fp32
    float* __restrict__ out,                  // [8,14,64,64,64] fp32 (y = h + x)
    unsigned short* __restrict__ hb0,         // [8,64,64,64] bf16
    unsigned short* __restrict__ hb1,         // [8,64,64,64] bf16
    unsigned* __restrict__ bar)               // {cnt, gen}
{
    __shared__ __align__(16) float smem[64 * 260];   // 66560 B; aliased as A-tile
    unsigned short* aT = (unsigned short*)smem;

    const int tid = threadIdx.x;
    const int l   = tid & 63;
    const int w   = tid >> 6;          // wave id == gate id
    const int y   = blockIdx.x & 63;
    const int b   = blockIdx.x >> 6;
    const int m16 = l & 15;
    const int q   = l >> 4;

    // hoisted per-lane bias (depends only on output column n)
    float bv[4];
    #pragma unroll
    for (int nt = 0; nt < 4; ++nt) bv[nt] = bias[w * 64 + nt * 16 + m16];

    // staging constants
    const int col = (tid >> 2) + 1;
    const int ch  = (tid & 3) * 16;
    const int sm  = (col & 7) << 3;            // swizzle mask for this col

    // epilogue constants
    const int fch   = (tid & 15) * 4;
    const int mbase = tid >> 4;

    float creg[16];                            // c state: 4 px-groups x 4 ch

    for (int t = 0; t < T_; ++t) {
        const unsigned short* hprev = (t & 1) ? hb0 : hb1;
        unsigned short* hnext       = (t & 1) ? hb1 : hb0;
        const float* xbase = x + (size_t)(b * T_ + t) * IMG;

        if (t) grid_barrier(bar, bar + 1);   // h(t-1) fully written, device-visible

        // ---- stage x rows (fp32 -> bf16), swizzled writes ----
        #pragma unroll
        for (int r = 0; r < 3; ++r) {
            int iy = y + r - 1;
            uint4 u0 = {0, 0, 0, 0}, u1 = {0, 0, 0, 0};
            if ((unsigned)iy < (unsigned)HH) {
                const float4* s4 = (const float4*)(xbase + iy * (WW * CC)) + tid * 4;
                float4 f0 = s4[0], f1 = s4[1], f2 = s4[2], f3 = s4[3];
                u0.x = pack2(f0.x, f0.y); u0.y = pack2(f0.z, f0.w);
                u0.z = pack2(f1.x, f1.y); u0.w = pack2(f1.z, f1.w);
                u1.x = pack2(f2.x, f2.y); u1.y = pack2(f2.z, f2.w);
                u1.z = pack2(f3.x, f3.y); u1.w = pack2(f3.z, f3.w);
            }
            *(uint4*)(aT + AT(0, r, col, ch ^ sm))       = u0;
            *(uint4*)(aT + AT(0, r, col, (ch + 8) ^ sm)) = u1;
        }
        // ---- stage h rows (bf16 copy); zeros at t==0 or OOB row ----
        #pragma unroll
        for (int r = 0; r < 3; ++r) {
            int iy = y + r - 1;
            uint4 u0 = {0, 0, 0, 0}, u1 = {0, 0, 0, 0};
            if (t && (unsigned)iy < (unsigned)HH) {
                const uint4* hp = (const uint4*)(hprev + (size_t)(b * HH + iy) * (WW * CC));
                u0 = hp[tid * 2];
                u1 = hp[tid * 2 + 1];
            }
            *(uint4*)(aT + AT(1, r, col, ch ^ sm))       = u0;
            *(uint4*)(aT + AT(1, r, col, (ch + 8) ^ sm)) = u1;
        }
        // ---- zero halo cols 0/65 (every step: z-transpose aliases them) ----
        if (tid < 96) {
            int grp = tid >> 3, l8 = tid & 7;
            int src = grp / 6, rem = grp % 6;
            int r = rem >> 1, colh = (rem & 1) * 65;
            int hm = (colh & 7) << 3;
            uint4 z = {0, 0, 0, 0};
            *(uint4*)(aT + AT(src, r, colh, (l8 * 8) ^ hm)) = z;
        }
        __syncthreads();

        // ---- accumulators init with bias ----
        floatx4 acc[4][4];
        #pragma unroll
        for (int nt = 0; nt < 4; ++nt) {
            #pragma unroll
            for (int mt = 0; mt < 4; ++mt) {
                acc[mt][nt][0] = bv[nt]; acc[mt][nt][1] = bv[nt];
                acc[mt][nt][2] = bv[nt]; acc[mt][nt][3] = bv[nt];
            }
        }

        // ---- K loop: 9 taps x {x,h} x 2 k-chunks of 32 ----
        // (t==0: h-region is zeros -> src=1 contributes 0, still correct)
        #pragma unroll
        for (int ky = 0; ky < 3; ++ky) {
            #pragma unroll
            for (int kx = 0; kx < 3; ++kx) {
                const int swz = ((m16 + kx) & 7) << 3;
                #pragma unroll
                for (int src = 0; src < 2; ++src) {
                    #pragma unroll
                    for (int g = 0; g < 2; ++g) {
                        const int lo = (g * 32 + q * 8) ^ swz;
                        short8 af[4];
                        #pragma unroll
                        for (int mt = 0; mt < 4; ++mt) {
                            int colr = mt * 16 + m16 + kx;   // 0..65
                            af[mt] = *(const short8*)(aT + AT(src, ky, colr, lo));
                        }
                        short8 bf[4];
                        int fc = (((src * 9 + ky * 3 + kx) * 2 + g) * 16 + w * 4);
                        #pragma unroll
                        for (int nt = 0; nt < 4; ++nt) {
                            bf[nt] = *(const short8*)(Wt + (size_t)(fc + nt) * 512 + l * 8);
                        }
                        #pragma unroll
                        for (int mt = 0; mt < 4; ++mt) {
                            #pragma unroll
                            for (int nt = 0; nt < 4; ++nt) {
                                acc[mt][nt] = __builtin_amdgcn_mfma_f32_16x16x32_bf16(
                                    af[mt], bf[nt], acc[mt][nt], 0, 0, 0);
                            }
                        }
                    }
                }
            }
        }

        // ---- transpose z through LDS: zT[64 m][260 pad] fp32 ----
        __syncthreads();   // all waves done reading aT
        #pragma unroll
        for (int mt = 0; mt < 4; ++mt) {
            #pragma unroll
            for (int nt = 0; nt < 4; ++nt) {
                int n = w * 64 + nt * 16 + m16;
                #pragma unroll
                for (int r = 0; r < 4; ++r) {
                    int m = mt * 16 + q * 4 + r;
                    smem[m * 260 + n] = acc[mt][nt][r];
                }
            }
        }
        __syncthreads();

        // ---- gates, cell update (c in regs), h, fused residual ----
        const float* xres = xbase + y * (WW * CC);
        float* outrow = out + (size_t)(b * T_ + t) * IMG + y * (WW * CC);
        unsigned short* hrow = hnext + (size_t)(b * HH + y) * (WW * CC);
        #pragma unroll
        for (int i = 0; i < 4; ++i) {
            int m = mbase + i * 16;
            const float* zr = smem + m * 260;
            float4 zi = *(const float4*)(zr + fch);
            float4 zf = *(const float4*)(zr + 64 + fch);
            float4 zg = *(const float4*)(zr + 128 + fch);
            float4 zo = *(const float4*)(zr + 192 + fch);
            float4 xv = *(const float4*)(xres + m * 64 + fch);

            float zia[4] = {zi.x, zi.y, zi.z, zi.w};
            float zfa[4] = {zf.x, zf.y, zf.z, zf.w};
            float zga[4] = {zg.x, zg.y, zg.z, zg.w};
            float zoa[4] = {zo.x, zo.y, zo.z, zo.w};
            float xa[4]  = {xv.x, xv.y, xv.z, xv.w};
            float hv[4];
            #pragma unroll
            for (int k = 0; k < 4; ++k) {
                float ig = hsig(zia[k]);
                float fg = hsig(zfa[k]);
                float gg = tanh_fast(zga[k]);
                float og = hsig(zoa[k]);
                float cn = (t == 0) ? (ig * gg) : fmaf(fg, creg[i * 4 + k], ig * gg);
                creg[i * 4 + k] = cn;
                hv[k] = og * tanh_fast(cn);
            }
            ushort4 hb;
            hb.x = bf16_of(hv[0]); hb.y = bf16_of(hv[1]);
            hb.z = bf16_of(hv[2]); hb.w = bf16_of(hv[3]);
            *(ushort4*)(hrow + m * 64 + fch) = hb;
            float4 yo = {hv[0] + xa[0], hv[1] + xa[1], hv[2] + xa[2], hv[3] + xa[3]};
            *(float4*)(outrow + m * 64 + fch) = yo;
        }
    }
}

extern "C" void kernel_launch(void* const* d_in, const int* in_sizes, int n_in,
                              void* d_out, int out_size, void* d_ws, size_t ws_size,
                              hipStream_t stream) {
    const float* x    = (const float*)d_in[0];
    const float* Wx   = (const float*)d_in[1];
    const float* Wh   = (const float*)d_in[2];
    const float* bias = (const float*)d_in[3];
    float* out = (float*)d_out;

    unsigned short* Wt = (unsigned short*)((char*)d_ws + WT_OFF);
    unsigned short* h0 = (unsigned short*)((char*)d_ws + H0_OFF);
    unsigned short* h1 = (unsigned short*)((char*)d_ws + H1_OFF);
    unsigned* bar      = (unsigned*)((char*)d_ws + BAR_OFF);

    repack_weights<<<144, 256, 0, stream>>>(Wx, Wh, Wt, bar);

    // 512 blocks = 256 CUs x 2 blocks/CU (launch_bounds(256,2), LDS 66.5 KB):
    // all co-resident, so the software grid barrier is sound.
    lstm_persistent<<<NBLK, 256, 0, stream>>>(x, Wt, bias, out, h0, h1, bar);
}

// Round 7
// 964.044 us; speedup vs baseline: 2.4916x; 2.4916x over previous
//
#include <hip/hip_runtime.h>

#define B_ 8
#define T_ 14
#define HH 64
#define WW 64
#define CC 64
#define IMG (HH*WW*CC)  // 262144 elems per (b,t) image

typedef __attribute__((ext_vector_type(8))) short short8;
typedef __attribute__((ext_vector_type(4))) float floatx4;

// ws layout (bytes):
//   [0, 589824)                 Wt: bf16 weights in MFMA B-fragment-major order
//   [1 MB, 9 MB)                c state fp32 [8][64][64][64]
//   [9 MB, 13 MB)               h ping bf16 [8][64][64][64]  (linear)
//   [13 MB, 17 MB)              h pong bf16                   (linear)
#define WT_OFF   0
#define C_OFF    (1u << 20)
#define H0_OFF   (C_OFF + 8u * 1024 * 1024)
#define H1_OFF   (H0_OFF + 4u * 1024 * 1024)

__device__ __forceinline__ unsigned short bf16_of(float f) {
    unsigned int x = __float_as_uint(f);
    unsigned int r = (x + 0x7FFFu + ((x >> 16) & 1u)) >> 16;  // RTNE
    return (unsigned short)r;
}
__device__ __forceinline__ unsigned int pack2(float a, float b) {
    return (unsigned int)bf16_of(a) | ((unsigned int)bf16_of(b) << 16);
}
__device__ __forceinline__ float hsig(float z) {
    return fminf(fmaxf(fmaf(z, 0.2f, 0.5f), 0.0f), 1.0f);
}
__device__ __forceinline__ float tanh_fast(float v) {
    float e = __expf(2.0f * v);
    return 1.0f - 2.0f / (e + 1.0f);
}

// Repack Wx,Wh [3,3,64,256] fp32 -> bf16 B-fragment-major:
// chunk fc = ((src*9+tap)*2+g)*16 + ntile ; element [lane][j] (j=0..7 contiguous)
// value = W[tap*64 + (g*32 + (lane>>4)*8 + j)]*256 + ntile*16 + (lane&15)
__global__ void repack_weights(const float* __restrict__ Wx,
                               const float* __restrict__ Wh,
                               unsigned short* __restrict__ Wt) {
    int u = blockIdx.x * 256 + threadIdx.x;    // 36864 threads
    int l  = u & 63;
    int nt = (u >> 6) & 15;
    int g  = (u >> 10) & 1;
    int st = u >> 11;                          // src*9 + tap, 0..17
    const float* W = (st < 9) ? Wx : Wh;
    int tap = (st < 9) ? st : st - 9;
    int n  = nt * 16 + (l & 15);
    int c0 = g * 32 + (l >> 4) * 8;
    unsigned short tmp[8];
    #pragma unroll
    for (int j = 0; j < 8; ++j) {
        tmp[j] = bf16_of(W[(tap * 64 + c0 + j) * 256 + n]);
    }
    *(uint4*)(Wt + (size_t)u * 8) = *(const uint4*)tmp;
}

// LDS A-tile: bf16 [src 2][plane 4][col 66][ch 64]; col 0 and 65 zero halo.
// plane p holds input row iy = y0 + p - 1 (a row PAIR needs 4 input rows).
// XOR-swizzled: logical (col, c) lives at element (col, c ^ ((col&7)<<3)).
// Both staging writes and K-loop reads apply the same XOR (both-sides rule).
#define AT(s, p, col, c) ((((s) * 4 + (p)) * 66 + (col)) * 64 + (c))

// One ConvLSTM timestep, M=128 implicit GEMM.
// Block = one image ROW PAIR (b, y0..y0+1): M=128 px, N=256 gate-ch,
// K=18 taps x 64. 4 waves; wave w owns gate w (n in [64w, 64w+64)).
// vs the M=64 version: each weight fragment read from L2 feeds 2x the
// output rows -> per-CU weight L2 traffic halves (1.18 MB -> 589 KB/step).
template<bool FIRST>
__global__ __launch_bounds__(256, 2) void lstm_step_mfma(
    const float* __restrict__ x,          // [8,14,64,64,64] fp32
    const unsigned short* __restrict__ Wt,// repacked bf16 weights
    const float* __restrict__ bias,       // [256] fp32
    float* __restrict__ out,              // [8,14,64,64,64] fp32 (y = h + x)
    float* __restrict__ cst,              // [8,64,64,64] fp32
    const unsigned short* __restrict__ hprev, // [8,64,64,64] bf16
    unsigned short* __restrict__ hnext,       // [8,64,64,64] bf16
    int t)
{
    __shared__ __align__(16) unsigned short aT[2 * 4 * 66 * 64];  // 67584 B
    float* zbuf = (float*)aT;   // aliased z half-buffer [64][260] = 66560 B

    const int tid = threadIdx.x;
    const int l   = tid & 63;
    const int w   = tid >> 6;          // wave id == gate id
    const int y0  = (blockIdx.x & 31) * 2;
    const int b   = blockIdx.x >> 5;
    const int m16 = l & 15;
    const int q   = l >> 4;

    const float* xbase = x + (size_t)(b * T_ + t) * IMG;

    // ---- stage x planes (fp32 -> bf16), 16 elems/thread/plane, swizzled ----
    {
        const int col = (tid >> 2) + 1;
        const int ch  = (tid & 3) * 16;
        const int sm  = (col & 7) << 3;            // swizzle mask for this col
        #pragma unroll
        for (int r = 0; r < 4; ++r) {
            int iy = y0 + r - 1;
            uint4 u0 = {0, 0, 0, 0}, u1 = {0, 0, 0, 0};
            if ((unsigned)iy < (unsigned)HH) {
                const float4* s4 = (const float4*)(xbase + iy * (WW * CC)) + tid * 4;
                float4 f0 = s4[0], f1 = s4[1], f2 = s4[2], f3 = s4[3];
                u0.x = pack2(f0.x, f0.y); u0.y = pack2(f0.z, f0.w);
                u0.z = pack2(f1.x, f1.y); u0.w = pack2(f1.z, f1.w);
                u1.x = pack2(f2.x, f2.y); u1.y = pack2(f2.z, f2.w);
                u1.z = pack2(f3.x, f3.y); u1.w = pack2(f3.z, f3.w);
            }
            *(uint4*)(aT + AT(0, r, col, ch ^ sm))       = u0;
            *(uint4*)(aT + AT(0, r, col, (ch + 8) ^ sm)) = u1;
        }
        // ---- stage h planes (bf16 copy); skipped entirely on first step ----
        if (!FIRST) {
            #pragma unroll
            for (int r = 0; r < 4; ++r) {
                int iy = y0 + r - 1;
                uint4 u0 = {0, 0, 0, 0}, u1 = {0, 0, 0, 0};
                if ((unsigned)iy < (unsigned)HH) {
                    const uint4* hp = (const uint4*)(hprev + (size_t)(b * HH + iy) * (WW * CC));
                    u0 = hp[tid * 2];
                    u1 = hp[tid * 2 + 1];
                }
                *(uint4*)(aT + AT(1, r, col, ch ^ sm))       = u0;
                *(uint4*)(aT + AT(1, r, col, (ch + 8) ^ sm)) = u1;
            }
        }
        // ---- zero halo cols 0/65: 2 src x 4 planes x 2 cols x 8 chunks ----
        if (tid < 128) {
            int grp = tid >> 3, l8 = tid & 7;
            int src = grp >> 3, rem = grp & 7;
            int p = rem >> 1, colh = (rem & 1) * 65;
            int hm = (colh & 7) << 3;
            uint4 z = {0, 0, 0, 0};
            *(uint4*)(aT + AT(src, p, colh, (l8 * 8) ^ hm)) = z;
        }
    }
    __syncthreads();

    // ---- accumulators init with bias (bias depends only on column n) ----
    float bv[4];
    #pragma unroll
    for (int nt = 0; nt < 4; ++nt) bv[nt] = bias[w * 64 + nt * 16 + m16];
    floatx4 acc[8][4];
    #pragma unroll
    for (int mt = 0; mt < 8; ++mt) {
        #pragma unroll
        for (int nt = 0; nt < 4; ++nt) {
            acc[mt][nt][0] = bv[nt]; acc[mt][nt][1] = bv[nt];
            acc[mt][nt][2] = bv[nt]; acc[mt][nt][3] = bv[nt];
        }
    }

    // ---- K loop: 9 taps x {x,h} x 2 k-chunks of 32; m-tile mt: row half
    // (mt>>2) selects plane (mt>>2)+ky, in-row tile (mt&3) ----
    const int NSRC = FIRST ? 1 : 2;
    #pragma unroll
    for (int ky = 0; ky < 3; ++ky) {
        #pragma unroll
        for (int kx = 0; kx < 3; ++kx) {
            // col = (mt&3)*16 + m16 + kx, (mt&3)*16 % 8 == 0 -> col&7 = (m16+kx)&7
            const int swz = ((m16 + kx) & 7) << 3;
            #pragma unroll
            for (int src = 0; src < NSRC; ++src) {
                #pragma unroll
                for (int g = 0; g < 2; ++g) {
                    const int lo = (g * 32 + q * 8) ^ swz;
                    short8 af[8];
                    #pragma unroll
                    for (int mt = 0; mt < 8; ++mt) {
                        int p    = (mt >> 2) + ky;          // 0..4
                        int colr = (mt & 3) * 16 + m16 + kx; // 0..65
                        af[mt] = *(const short8*)(aT + AT(src, p, colr, lo));
                    }
                    short8 bf[4];
                    int fc = (((src * 9 + ky * 3 + kx) * 2 + g) * 16 + w * 4);
                    #pragma unroll
                    for (int nt = 0; nt < 4; ++nt) {
                        bf[nt] = *(const short8*)(Wt + (size_t)(fc + nt) * 512 + l * 8);
                    }
                    #pragma unroll
                    for (int mt = 0; mt < 8; ++mt) {
                        #pragma unroll
                        for (int nt = 0; nt < 4; ++nt) {
                            acc[mt][nt] = __builtin_amdgcn_mfma_f32_16x16x32_bf16(
                                af[mt], bf[nt], acc[mt][nt], 0, 0, 0);
                        }
                    }
                }
            }
        }
    }

    // ---- two-half epilogue: z half (64x260 fp32) aliases the A-tile ----
    const int fch   = (tid & 15) * 4;
    const int mbase = tid >> 4;
    #pragma unroll
    for (int hf = 0; hf < 2; ++hf) {
        __syncthreads();   // hf=0: aT reads done; hf=1: half-0 z reads done
        #pragma unroll
        for (int mt4 = 0; mt4 < 4; ++mt4) {
            #pragma unroll
            for (int nt = 0; nt < 4; ++nt) {
                int n = w * 64 + nt * 16 + m16;
                #pragma unroll
                for (int r = 0; r < 4; ++r) {
                    int m = mt4 * 16 + q * 4 + r;
                    zbuf[m * 260 + n] = acc[hf * 4 + mt4][nt][r];
                }
            }
        }
        __syncthreads();

        const int yo = y0 + hf;
        const float* xres = xbase + yo * (WW * CC);
        float* outrow = out + (size_t)(b * T_ + t) * IMG + yo * (WW * CC);
        #pragma unroll
        for (int i = 0; i < 4; ++i) {
            int m = mbase + i * 16;
            const float* zr = zbuf + m * 260;
            float4 zi = *(const float4*)(zr + fch);
            float4 zf = *(const float4*)(zr + 64 + fch);
            float4 zg = *(const float4*)(zr + 128 + fch);
            float4 zo = *(const float4*)(zr + 192 + fch);
            size_t sidx = (size_t)(b * HH + yo) * (WW * CC) + m * 64 + fch;
            float4 cold = {0, 0, 0, 0};
            if (!FIRST) cold = *(const float4*)(cst + sidx);
            float4 xv = *(const float4*)(xres + m * 64 + fch);

            float cn[4], hv[4];
            float zia[4] = {zi.x, zi.y, zi.z, zi.w};
            float zfa[4] = {zf.x, zf.y, zf.z, zf.w};
            float zga[4] = {zg.x, zg.y, zg.z, zg.w};
            float zoa[4] = {zo.x, zo.y, zo.z, zo.w};
            float ca[4]  = {cold.x, cold.y, cold.z, cold.w};
            float xa[4]  = {xv.x, xv.y, xv.z, xv.w};
            #pragma unroll
            for (int k = 0; k < 4; ++k) {
                float ig = hsig(zia[k]);
                float fg = hsig(zfa[k]);
                float gg = tanh_fast(zga[k]);
                float og = hsig(zoa[k]);
                cn[k] = FIRST ? (ig * gg) : fmaf(fg, ca[k], ig * gg);
                hv[k] = og * tanh_fast(cn[k]);
            }
            float4 cnew = {cn[0], cn[1], cn[2], cn[3]};
            *(float4*)(cst + sidx) = cnew;
            ushort4 hb;
            hb.x = bf16_of(hv[0]); hb.y = bf16_of(hv[1]);
            hb.z = bf16_of(hv[2]); hb.w = bf16_of(hv[3]);
            *(ushort4*)(hnext + sidx) = hb;
            float4 yv = {hv[0] + xa[0], hv[1] + xa[1], hv[2] + xa[2], hv[3] + xa[3]};
            *(float4*)(outrow + m * 64 + fch) = yv;
        }
    }
}

extern "C" void kernel_launch(void* const* d_in, const int* in_sizes, int n_in,
                              void* d_out, int out_size, void* d_ws, size_t ws_size,
                              hipStream_t stream) {
    const float* x    = (const float*)d_in[0];
    const float* Wx   = (const float*)d_in[1];
    const float* Wh   = (const float*)d_in[2];
    const float* bias = (const float*)d_in[3];
    float* out = (float*)d_out;

    unsigned short* Wt = (unsigned short*)((char*)d_ws + WT_OFF);
    float* cst         = (float*)((char*)d_ws + C_OFF);
    unsigned short* h0 = (unsigned short*)((char*)d_ws + H0_OFF);
    unsigned short* h1 = (unsigned short*)((char*)d_ws + H1_OFF);

    repack_weights<<<144, 256, 0, stream>>>(Wx, Wh, Wt);

    const int grid = B_ * (HH / 2);  // 256 blocks: one image row PAIR each
    lstm_step_mfma<true><<<grid, 256, 0, stream>>>(x, Wt, bias, out, cst, h0, h0, 0);
    for (int t = 1; t < T_; ++t) {
        unsigned short* hp = (t & 1) ? h0 : h1;   // written by step t-1
        unsigned short* hn = (t & 1) ? h1 : h0;
        lstm_step_mfma<false><<<grid, 256, 0, stream>>>(x, Wt, bias, out, cst, hp, hn, t);
    }
}

// Round 8
// 520.518 us; speedup vs baseline: 4.6146x; 1.8521x over previous
//
#include <hip/hip_runtime.h>

#define B_ 8
#define T_ 14
#define HH 64
#define WW 64
#define CC 64
#define FF 64
#define IMG (HH*WW*CC)  // 262144 elems per (b,t) image

typedef __attribute__((ext_vector_type(8))) short short8;
typedef __attribute__((ext_vector_type(4))) float floatx4;

// ws layout (bytes):
//   [0, 589824)                 Wt: bf16 weights in MFMA B-fragment-major order
//   [1 MB, 9 MB)                c state fp32 [8][64][64][64]
//   [9 MB, 13 MB)               h ping bf16 [8][64][64][64]  (linear)
//   [13 MB, 17 MB)              h pong bf16                   (linear)
#define WT_OFF   0
#define C_OFF    (1u << 20)
#define H0_OFF   (C_OFF + 8u * 1024 * 1024)
#define H1_OFF   (H0_OFF + 4u * 1024 * 1024)

__device__ __forceinline__ unsigned short bf16_of(float f) {
    unsigned int x = __float_as_uint(f);
    unsigned int r = (x + 0x7FFFu + ((x >> 16) & 1u)) >> 16;  // RTNE
    return (unsigned short)r;
}
__device__ __forceinline__ unsigned int pack2(float a, float b) {
    return (unsigned int)bf16_of(a) | ((unsigned int)bf16_of(b) << 16);
}
__device__ __forceinline__ float hsig(float z) {
    return fminf(fmaxf(fmaf(z, 0.2f, 0.5f), 0.0f), 1.0f);
}
__device__ __forceinline__ float tanh_fast(float v) {
    float e = __expf(2.0f * v);
    return 1.0f - 2.0f / (e + 1.0f);
}

// Repack Wx,Wh [3,3,64,256] fp32 -> bf16 B-fragment-major:
// chunk fc = ((src*9+tap)*2+g)*16 + ntile ; element [lane][j] (j=0..7 contiguous)
// value = W[tap*64 + (g*32 + (lane>>4)*8 + j)]*256 + ntile*16 + (lane&15)
__global__ void repack_weights(const float* __restrict__ Wx,
                               const float* __restrict__ Wh,
                               unsigned short* __restrict__ Wt) {
    int u = blockIdx.x * 256 + threadIdx.x;    // 36864 threads
    int l  = u & 63;
    int nt = (u >> 6) & 15;
    int g  = (u >> 10) & 1;
    int st = u >> 11;                          // src*9 + tap, 0..17
    const float* W = (st < 9) ? Wx : Wh;
    int tap = (st < 9) ? st : st - 9;
    int n  = nt * 16 + (l & 15);
    int c0 = g * 32 + (l >> 4) * 8;
    unsigned short tmp[8];
    #pragma unroll
    for (int j = 0; j < 8; ++j) {
        tmp[j] = bf16_of(W[(tap * 64 + c0 + j) * 256 + n]);
    }
    *(uint4*)(Wt + (size_t)u * 8) = *(const uint4*)tmp;
}

// LDS A-tile: bf16 [src 2][ky 3][col 66][ch 64]; col 0 and 65 are zero halo.
// XOR-swizzled: logical (col, c) lives at element (col, c ^ ((col&7)<<3)).
// Both staging writes and K-loop reads apply the same XOR (both-sides rule).
#define AT(s, r, col, c) ((((s) * 3 + (r)) * 66 + (col)) * 64 + (c))

// One ConvLSTM timestep as implicit GEMM, 8-WAVE blocks for occupancy.
// Block = one image row (b,y): M=64 px, N=256 gate-ch, K=18 taps x 64.
// 512 threads = 8 waves; wave w = (gate = w&3, n-half = w>>2) owns an
// (M=64, N=32) output slab. Round-7's inverse experiment (waves/SIMD
// 2->1 doubled time despite halved weight bytes) showed the kernel is
// latency-bound: this doubles waves/SIMD to 4 at unchanged B-L2 bytes/CU.
template<bool FIRST>
__global__ __launch_bounds__(512, 4) void lstm_step_mfma(
    const float* __restrict__ x,          // [8,14,64,64,64] fp32
    const unsigned short* __restrict__ Wt,// repacked bf16 weights
    const float* __restrict__ bias,       // [256] fp32
    float* __restrict__ out,              // [8,14,64,64,64] fp32 (y = h + x)
    float* __restrict__ cst,              // [8,64,64,64] fp32
    const unsigned short* __restrict__ hprev, // [8,64,64,64] bf16
    unsigned short* __restrict__ hnext,       // [8,64,64,64] bf16
    int t)
{
    __shared__ __align__(16) float smem[64 * 260];   // 66560 B; aliased as A-tile
    unsigned short* aT = (unsigned short*)smem;

    const int tid  = threadIdx.x;       // 0..511
    const int l    = tid & 63;
    const int w    = tid >> 6;          // wave id 0..7
    const int gate = w & 3;
    const int nh   = w >> 2;            // n-half within the gate
    const int y    = blockIdx.x & 63;
    const int b    = blockIdx.x >> 6;
    const int m16  = l & 15;
    const int q    = l >> 4;

    const float* xbase = x + (size_t)(b * T_ + t) * IMG;

    // ---- stage x rows (fp32 -> bf16), 8 elems/thread/row, swizzled writes ----
    {
        const int col = (tid >> 3) + 1;            // 1..64
        const int ch8 = (tid & 7) * 8;
        const int sm  = (col & 7) << 3;            // swizzle mask for this col
        #pragma unroll
        for (int r = 0; r < 3; ++r) {
            int iy = y + r - 1;
            uint4 u = {0, 0, 0, 0};
            if ((unsigned)iy < (unsigned)HH) {
                const float4* s4 = (const float4*)(xbase + iy * (WW * CC));
                float4 f0 = s4[tid * 2], f1 = s4[tid * 2 + 1];
                u.x = pack2(f0.x, f0.y); u.y = pack2(f0.z, f0.w);
                u.z = pack2(f1.x, f1.y); u.w = pack2(f1.z, f1.w);
            }
            *(uint4*)(aT + AT(0, r, col, ch8 ^ sm)) = u;
        }
        // ---- stage h rows (bf16 copy), or zeros on first step ----
        #pragma unroll
        for (int r = 0; r < 3; ++r) {
            int iy = y + r - 1;
            uint4 u = {0, 0, 0, 0};
            if (!FIRST && (unsigned)iy < (unsigned)HH) {
                u = ((const uint4*)(hprev + (size_t)(b * HH + iy) * (WW * CC)))[tid];
            }
            *(uint4*)(aT + AT(1, r, col, ch8 ^ sm)) = u;
        }
        // ---- zero halo columns 0 and 65 (swizzled addresses, zero data) ----
        if (tid < 96) {
            int grp = tid >> 3, l8 = tid & 7;
            int src = grp / 6, rem = grp % 6;
            int r = rem >> 1, colh = (rem & 1) * 65;
            int hm = (colh & 7) << 3;
            uint4 z = {0, 0, 0, 0};
            *(uint4*)(aT + AT(src, r, colh, (l8 * 8) ^ hm)) = z;
        }
    }
    __syncthreads();

    // ---- accumulators init with bias (bias depends only on column n) ----
    floatx4 acc[4][2];
    #pragma unroll
    for (int nt = 0; nt < 2; ++nt) {
        float bv = bias[gate * 64 + nh * 32 + nt * 16 + m16];
        #pragma unroll
        for (int mt = 0; mt < 4; ++mt) {
            acc[mt][nt][0] = bv; acc[mt][nt][1] = bv;
            acc[mt][nt][2] = bv; acc[mt][nt][3] = bv;
        }
    }

    // ---- K loop: 9 taps x {x,h} x 2 k-chunks of 32 ----
    const int NSRC = FIRST ? 1 : 2;
    #pragma unroll
    for (int ky = 0; ky < 3; ++ky) {
        #pragma unroll
        for (int kx = 0; kx < 3; ++kx) {
            // col = mt*16 + m16 + kx and mt*16 % 8 == 0, so (col&7) = (m16+kx)&7
            const int swz = ((m16 + kx) & 7) << 3;
            #pragma unroll
            for (int src = 0; src < NSRC; ++src) {
                #pragma unroll
                for (int g = 0; g < 2; ++g) {
                    const int lo = (g * 32 + q * 8) ^ swz;
                    short8 af[4];
                    #pragma unroll
                    for (int mt = 0; mt < 4; ++mt) {
                        int col = mt * 16 + m16 + kx;   // 0..65 (halo handles kx-1)
                        af[mt] = *(const short8*)(aT + AT(src, ky, col, lo));
                    }
                    short8 bf[2];
                    int fc = (((src * 9 + ky * 3 + kx) * 2 + g) * 16
                              + gate * 4 + nh * 2);
                    #pragma unroll
                    for (int nt = 0; nt < 2; ++nt) {
                        bf[nt] = *(const short8*)(Wt + (size_t)(fc + nt) * 512 + l * 8);
                    }
                    #pragma unroll
                    for (int mt = 0; mt < 4; ++mt) {
                        #pragma unroll
                        for (int nt = 0; nt < 2; ++nt) {
                            acc[mt][nt] = __builtin_amdgcn_mfma_f32_16x16x32_bf16(
                                af[mt], bf[nt], acc[mt][nt], 0, 0, 0);
                        }
                    }
                }
            }
        }
    }

    // ---- transpose z through LDS: zT[64 m][260 pad] fp32 ----
    __syncthreads();   // all waves done reading aT
    #pragma unroll
    for (int mt = 0; mt < 4; ++mt) {
        #pragma unroll
        for (int nt = 0; nt < 2; ++nt) {
            int n = gate * 64 + nh * 32 + nt * 16 + m16;
            #pragma unroll
            for (int r = 0; r < 4; ++r) {
                int m = mt * 16 + q * 4 + r;
                smem[m * 260 + n] = acc[mt][nt][r];
            }
        }
    }
    __syncthreads();

    // ---- gates, cell update, h, fused residual (2 m-rows per thread) ----
    const int fch  = (tid & 15) * 4;
    const int mrow = tid >> 4;                     // 0..31
    const float* xres = xbase + y * (WW * CC);
    float* outrow = out + (size_t)(b * T_ + t) * IMG + y * (WW * CC);
    #pragma unroll
    for (int i = 0; i < 2; ++i) {
        int m = mrow + i * 32;
        const float* zr = smem + m * 260;
        float4 zi = *(const float4*)(zr + fch);
        float4 zf = *(const float4*)(zr + 64 + fch);
        float4 zg = *(const float4*)(zr + 128 + fch);
        float4 zo = *(const float4*)(zr + 192 + fch);
        size_t sidx = (size_t)(b * HH + y) * (WW * CC) + m * 64 + fch;
        float4 cold = {0, 0, 0, 0};
        if (!FIRST) cold = *(const float4*)(cst + sidx);
        float4 xv = *(const float4*)(xres + m * 64 + fch);

        float cn[4], hv[4];
        float zia[4] = {zi.x, zi.y, zi.z, zi.w};
        float zfa[4] = {zf.x, zf.y, zf.z, zf.w};
        float zga[4] = {zg.x, zg.y, zg.z, zg.w};
        float zoa[4] = {zo.x, zo.y, zo.z, zo.w};
        float ca[4]  = {cold.x, cold.y, cold.z, cold.w};
        float xa[4]  = {xv.x, xv.y, xv.z, xv.w};
        #pragma unroll
        for (int k = 0; k < 4; ++k) {
            float ig = hsig(zia[k]);
            float fg = hsig(zfa[k]);
            float gg = tanh_fast(zga[k]);
            float og = hsig(zoa[k]);
            cn[k] = FIRST ? (ig * gg) : fmaf(fg, ca[k], ig * gg);
            hv[k] = og * tanh_fast(cn[k]);
        }
        float4 cnew = {cn[0], cn[1], cn[2], cn[3]};
        *(float4*)(cst + sidx) = cnew;
        ushort4 hb;
        hb.x = bf16_of(hv[0]); hb.y = bf16_of(hv[1]);
        hb.z = bf16_of(hv[2]); hb.w = bf16_of(hv[3]);
        *(ushort4*)(hnext + sidx) = hb;
        float4 yo = {hv[0] + xa[0], hv[1] + xa[1], hv[2] + xa[2], hv[3] + xa[3]};
        *(float4*)(outrow + m * 64 + fch) = yo;
    }
}

extern "C" void kernel_launch(void* const* d_in, const int* in_sizes, int n_in,
                              void* d_out, int out_size, void* d_ws, size_t ws_size,
                              hipStream_t stream) {
    const float* x    = (const float*)d_in[0];
    const float* Wx   = (const float*)d_in[1];
    const float* Wh   = (const float*)d_in[2];
    const float* bias = (const float*)d_in[3];
    float* out = (float*)d_out;

    unsigned short* Wt = (unsigned short*)((char*)d_ws + WT_OFF);
    float* cst         = (float*)((char*)d_ws + C_OFF);
    unsigned short* h0 = (unsigned short*)((char*)d_ws + H0_OFF);
    unsigned short* h1 = (unsigned short*)((char*)d_ws + H1_OFF);

    repack_weights<<<144, 256, 0, stream>>>(Wx, Wh, Wt);

    // 512 blocks x 512 threads: 2 blocks/CU (LDS 2x66560=133KB, VGPR<=128
    // via launch_bounds(512,4)) -> 16 waves/CU = 4 waves/SIMD.
    const int grid = B_ * HH;  // one image row each
    lstm_step_mfma<true><<<grid, 512, 0, stream>>>(x, Wt, bias, out, cst, h0, h0, 0);
    for (int t = 1; t < T_; ++t) {
        unsigned short* hp = (t & 1) ? h0 : h1;   // written by step t-1
        unsigned short* hn = (t & 1) ? h1 : h0;
        lstm_step_mfma<false><<<grid, 512, 0, stream>>>(x, Wt, bias, out, cst, hp, hn, t);
    }
}

// Round 9
// 493.112 us; speedup vs baseline: 4.8711x; 1.0556x over previous
//
#include <hip/hip_runtime.h>

#define B_ 8
#define T_ 14
#define HH 64
#define WW 64
#define CC 64
#define FF 64
#define IMG (HH*WW*CC)  // 262144 elems per (b,t) image

typedef __attribute__((ext_vector_type(8))) short short8;
typedef __attribute__((ext_vector_type(4))) float floatx4;

// ws layout (bytes):
//   [0, 589824)                 Wt: bf16 weights in MFMA B-fragment-major order
//   [1 MB, 9 MB)                c state fp32 [8][64][64][64]
//   [9 MB, 13 MB)               h ping bf16 [8][64][64][64]  (linear)
//   [13 MB, 17 MB)              h pong bf16                   (linear)
#define WT_OFF   0
#define C_OFF    (1u << 20)
#define H0_OFF   (C_OFF + 8u * 1024 * 1024)
#define H1_OFF   (H0_OFF + 4u * 1024 * 1024)

__device__ __forceinline__ unsigned short bf16_of(float f) {
    unsigned int x = __float_as_uint(f);
    unsigned int r = (x + 0x7FFFu + ((x >> 16) & 1u)) >> 16;  // RTNE
    return (unsigned short)r;
}
__device__ __forceinline__ unsigned int pack2(float a, float b) {
    return (unsigned int)bf16_of(a) | ((unsigned int)bf16_of(b) << 16);
}
__device__ __forceinline__ float hsig(float z) {
    return fminf(fmaxf(fmaf(z, 0.2f, 0.5f), 0.0f), 1.0f);
}
__device__ __forceinline__ float tanh_fast(float v) {
    float e = __expf(2.0f * v);
    return 1.0f - 2.0f / (e + 1.0f);
}

// Repack Wx,Wh [3,3,64,256] fp32 -> bf16 B-fragment-major:
// chunk fc = ((src*9+tap)*2+g)*16 + ntile ; element [lane][j] (j=0..7 contiguous)
// value = W[tap*64 + (g*32 + (lane>>4)*8 + j)]*256 + ntile*16 + (lane&15)
__global__ void repack_weights(const float* __restrict__ Wx,
                               const float* __restrict__ Wh,
                               unsigned short* __restrict__ Wt) {
    int u = blockIdx.x * 256 + threadIdx.x;    // 36864 threads
    int l  = u & 63;
    int nt = (u >> 6) & 15;
    int g  = (u >> 10) & 1;
    int st = u >> 11;                          // src*9 + tap, 0..17
    const float* W = (st < 9) ? Wx : Wh;
    int tap = (st < 9) ? st : st - 9;
    int n  = nt * 16 + (l & 15);
    int c0 = g * 32 + (l >> 4) * 8;
    unsigned short tmp[8];
    #pragma unroll
    for (int j = 0; j < 8; ++j) {
        tmp[j] = bf16_of(W[(tap * 64 + c0 + j) * 256 + n]);
    }
    *(uint4*)(Wt + (size_t)u * 8) = *(const uint4*)tmp;
}

// LDS A-tile: bf16 [src 2][ky 3][col 66][ch 64]; col 0 and 65 are zero halo.
// XOR-swizzled: logical (col, c) lives at element (col, c ^ ((col&7)<<3)).
// Both staging writes and K-loop reads apply the same XOR (both-sides rule).
#define AT(s, r, col, c) ((((s) * 3 + (r)) * 66 + (col)) * 64 + (c))

// One ConvLSTM timestep as implicit GEMM, 8-wave blocks.
// Block = one image row (b,y): M=64 px, N=256 gate-ch, K=18 taps x 64.
//
// XCD<->BATCH LOCALITY REMAP (this round's one change): b = bid&7, y = bid>>3.
// The dispatcher round-robins bid%8 across the 8 XCDs [learn_hip m09], so
// XCD x owns ALL 64 rows of batch x, every launch:
//  - x/h halo rows (y+-1) are read by blocks on the SAME XCD -> one L2 fill
//    instead of three (x fetch ~25 -> 8.4 MB/step; h refetch ~12.6 -> ~0),
//  - h producer (step t-1) and consumers (step t) share an L2 -> h stays
//    dirty-resident, never round-trips HBM,
//  - c rows (1.05 MB/XCD) stay L2-resident across launches -> the 33.6
//    MB/step c round-trip mostly vanishes.
// Mapping wrong on some dispatcher => exactly today's perf, no correctness risk.
template<bool FIRST>
__global__ __launch_bounds__(512, 4) void lstm_step_mfma(
    const float* __restrict__ x,          // [8,14,64,64,64] fp32
    const unsigned short* __restrict__ Wt,// repacked bf16 weights
    const float* __restrict__ bias,       // [256] fp32
    float* __restrict__ out,              // [8,14,64,64,64] fp32 (y = h + x)
    float* __restrict__ cst,              // [8,64,64,64] fp32
    const unsigned short* __restrict__ hprev, // [8,64,64,64] bf16
    unsigned short* __restrict__ hnext,       // [8,64,64,64] bf16
    int t)
{
    __shared__ __align__(16) float smem[64 * 260];   // 66560 B; aliased as A-tile
    unsigned short* aT = (unsigned short*)smem;

    const int tid  = threadIdx.x;       // 0..511
    const int l    = tid & 63;
    const int w    = tid >> 6;          // wave id 0..7
    const int gate = w & 3;
    const int nh   = w >> 2;            // n-half within the gate
    const int b    = blockIdx.x & 7;    // XCD-stable: bid%8 -> XCD -> batch
    const int y    = blockIdx.x >> 3;
    const int m16  = l & 15;
    const int q    = l >> 4;

    const float* xbase = x + (size_t)(b * T_ + t) * IMG;

    // ---- stage x rows (fp32 -> bf16), 8 elems/thread/row, swizzled writes ----
    {
        const int col = (tid >> 3) + 1;            // 1..64
        const int ch8 = (tid & 7) * 8;
        const int sm  = (col & 7) << 3;            // swizzle mask for this col
        #pragma unroll
        for (int r = 0; r < 3; ++r) {
            int iy = y + r - 1;
            uint4 u = {0, 0, 0, 0};
            if ((unsigned)iy < (unsigned)HH) {
                const float4* s4 = (const float4*)(xbase + iy * (WW * CC));
                float4 f0 = s4[tid * 2], f1 = s4[tid * 2 + 1];
                u.x = pack2(f0.x, f0.y); u.y = pack2(f0.z, f0.w);
                u.z = pack2(f1.x, f1.y); u.w = pack2(f1.z, f1.w);
            }
            *(uint4*)(aT + AT(0, r, col, ch8 ^ sm)) = u;
        }
        // ---- stage h rows (bf16 copy), or zeros on first step ----
        #pragma unroll
        for (int r = 0; r < 3; ++r) {
            int iy = y + r - 1;
            uint4 u = {0, 0, 0, 0};
            if (!FIRST && (unsigned)iy < (unsigned)HH) {
                u = ((const uint4*)(hprev + (size_t)(b * HH + iy) * (WW * CC)))[tid];
            }
            *(uint4*)(aT + AT(1, r, col, ch8 ^ sm)) = u;
        }
        // ---- zero halo columns 0 and 65 (swizzled addresses, zero data) ----
        if (tid < 96) {
            int grp = tid >> 3, l8 = tid & 7;
            int src = grp / 6, rem = grp % 6;
            int r = rem >> 1, colh = (rem & 1) * 65;
            int hm = (colh & 7) << 3;
            uint4 z = {0, 0, 0, 0};
            *(uint4*)(aT + AT(src, r, colh, (l8 * 8) ^ hm)) = z;
        }
    }
    __syncthreads();

    // ---- accumulators init with bias (bias depends only on column n) ----
    floatx4 acc[4][2];
    #pragma unroll
    for (int nt = 0; nt < 2; ++nt) {
        float bv = bias[gate * 64 + nh * 32 + nt * 16 + m16];
        #pragma unroll
        for (int mt = 0; mt < 4; ++mt) {
            acc[mt][nt][0] = bv; acc[mt][nt][1] = bv;
            acc[mt][nt][2] = bv; acc[mt][nt][3] = bv;
        }
    }

    // ---- K loop: 9 taps x {x,h} x 2 k-chunks of 32 ----
    const int NSRC = FIRST ? 1 : 2;
    #pragma unroll
    for (int ky = 0; ky < 3; ++ky) {
        #pragma unroll
        for (int kx = 0; kx < 3; ++kx) {
            // col = mt*16 + m16 + kx and mt*16 % 8 == 0, so (col&7) = (m16+kx)&7
            const int swz = ((m16 + kx) & 7) << 3;
            #pragma unroll
            for (int src = 0; src < NSRC; ++src) {
                #pragma unroll
                for (int g = 0; g < 2; ++g) {
                    const int lo = (g * 32 + q * 8) ^ swz;
                    short8 af[4];
                    #pragma unroll
                    for (int mt = 0; mt < 4; ++mt) {
                        int col = mt * 16 + m16 + kx;   // 0..65 (halo handles kx-1)
                        af[mt] = *(const short8*)(aT + AT(src, ky, col, lo));
                    }
                    short8 bf[2];
                    int fc = (((src * 9 + ky * 3 + kx) * 2 + g) * 16
                              + gate * 4 + nh * 2);
                    #pragma unroll
                    for (int nt = 0; nt < 2; ++nt) {
                        bf[nt] = *(const short8*)(Wt + (size_t)(fc + nt) * 512 + l * 8);
                    }
                    #pragma unroll
                    for (int mt = 0; mt < 4; ++mt) {
                        #pragma unroll
                        for (int nt = 0; nt < 2; ++nt) {
                            acc[mt][nt] = __builtin_amdgcn_mfma_f32_16x16x32_bf16(
                                af[mt], bf[nt], acc[mt][nt], 0, 0, 0);
                        }
                    }
                }
            }
        }
    }

    // ---- transpose z through LDS: zT[64 m][260 pad] fp32 ----
    __syncthreads();   // all waves done reading aT
    #pragma unroll
    for (int mt = 0; mt < 4; ++mt) {
        #pragma unroll
        for (int nt = 0; nt < 2; ++nt) {
            int n = gate * 64 + nh * 32 + nt * 16 + m16;
            #pragma unroll
            for (int r = 0; r < 4; ++r) {
                int m = mt * 16 + q * 4 + r;
                smem[m * 260 + n] = acc[mt][nt][r];
            }
        }
    }
    __syncthreads();

    // ---- gates, cell update, h, fused residual (2 m-rows per thread) ----
    const int fch  = (tid & 15) * 4;
    const int mrow = tid >> 4;                     // 0..31
    const float* xres = xbase + y * (WW * CC);
    float* outrow = out + (size_t)(b * T_ + t) * IMG + y * (WW * CC);
    #pragma unroll
    for (int i = 0; i < 2; ++i) {
        int m = mrow + i * 32;
        const float* zr = smem + m * 260;
        float4 zi = *(const float4*)(zr + fch);
        float4 zf = *(const float4*)(zr + 64 + fch);
        float4 zg = *(const float4*)(zr + 128 + fch);
        float4 zo = *(const float4*)(zr + 192 + fch);
        size_t sidx = (size_t)(b * HH + y) * (WW * CC) + m * 64 + fch;
        float4 cold = {0, 0, 0, 0};
        if (!FIRST) cold = *(const float4*)(cst + sidx);
        float4 xv = *(const float4*)(xres + m * 64 + fch);

        float cn[4], hv[4];
        float zia[4] = {zi.x, zi.y, zi.z, zi.w};
        float zfa[4] = {zf.x, zf.y, zf.z, zf.w};
        float zga[4] = {zg.x, zg.y, zg.z, zg.w};
        float zoa[4] = {zo.x, zo.y, zo.z, zo.w};
        float ca[4]  = {cold.x, cold.y, cold.z, cold.w};
        float xa[4]  = {xv.x, xv.y, xv.z, xv.w};
        #pragma unroll
        for (int k = 0; k < 4; ++k) {
            float ig = hsig(zia[k]);
            float fg = hsig(zfa[k]);
            float gg = tanh_fast(zga[k]);
            float og = hsig(zoa[k]);
            cn[k] = FIRST ? (ig * gg) : fmaf(fg, ca[k], ig * gg);
            hv[k] = og * tanh_fast(cn[k]);
        }
        float4 cnew = {cn[0], cn[1], cn[2], cn[3]};
        *(float4*)(cst + sidx) = cnew;
        ushort4 hb;
        hb.x = bf16_of(hv[0]); hb.y = bf16_of(hv[1]);
        hb.z = bf16_of(hv[2]); hb.w = bf16_of(hv[3]);
        *(ushort4*)(hnext + sidx) = hb;
        float4 yo = {hv[0] + xa[0], hv[1] + xa[1], hv[2] + xa[2], hv[3] + xa[3]};
        *(float4*)(outrow + m * 64 + fch) = yo;
    }
}

extern "C" void kernel_launch(void* const* d_in, const int* in_sizes, int n_in,
                              void* d_out, int out_size, void* d_ws, size_t ws_size,
                              hipStream_t stream) {
    const float* x    = (const float*)d_in[0];
    const float* Wx   = (const float*)d_in[1];
    const float* Wh   = (const float*)d_in[2];
    const float* bias = (const float*)d_in[3];
    float* out = (float*)d_out;

    unsigned short* Wt = (unsigned short*)((char*)d_ws + WT_OFF);
    float* cst         = (float*)((char*)d_ws + C_OFF);
    unsigned short* h0 = (unsigned short*)((char*)d_ws + H0_OFF);
    unsigned short* h1 = (unsigned short*)((char*)d_ws + H1_OFF);

    repack_weights<<<144, 256, 0, stream>>>(Wx, Wh, Wt);

    // 512 blocks x 512 threads: 2 blocks/CU -> 4 waves/SIMD; block->batch
    // mapping is bid%8 so each XCD keeps one batch's x/h/c in its own L2.
    const int grid = B_ * HH;
    lstm_step_mfma<true><<<grid, 512, 0, stream>>>(x, Wt, bias, out, cst, h0, h0, 0);
    for (int t = 1; t < T_; ++t) {
        unsigned short* hp = (t & 1) ? h0 : h1;   // written by step t-1
        unsigned short* hn = (t & 1) ? h1 : h0;
        lstm_step_mfma<false><<<grid, 512, 0, stream>>>(x, Wt, bias, out, cst, hp, hn, t);
    }
}